// Round 4
// baseline (512.309 us; speedup 1.0000x reference)
//
#include <hip/hip_runtime.h>

// CRF forward (log partition), B=256, T=2048, N=64, MI355X.
//
// Round 4: chunked scan. alpha_T = (prod_t M_t) . alpha_0 with
// M_t = diag(eu_t).E. Split T into C=8 chunks of L=256; each chunk's 64x64
// transfer matrix is computed by 4 waves (16 columns each) using the same
// MFMA step as before (psi-permuted A-fragments, zero-shuffle feedback) --
// the 16 output columns now carry 16 DISTINCT basis vectors instead of
// replicas. 8192 waves give ~12 waves/CU so load latency is hidden by TLP
// (rounds 2/3 were latency-bound at 1 wave/CU). A tiny combine kernel chains
// the 8 chunk matrices per batch in f32 with log2-domain exponent handling.

typedef __attribute__((ext_vector_type(4))) float f32x4;
typedef __attribute__((ext_vector_type(8))) short bf16x8;

namespace {
constexpr int kB = 256;
constexpr int kT = 2048;
constexpr int kN = 64;
constexpr int kC = 8;           // chunks
constexpr int kL = kT / kC;     // 256 steps per chunk
constexpr int kStart = 1;       // GO
constexpr int kEnd = 2;         // EOS
constexpr long kTileFloats = (long)kB * kC * 4 * 1024;  // 8192 tiles x 64x16
constexpr long kNumTiles = (long)kB * kC * 4;
}  // namespace

// ---------- pre-pass: eu_sw[b][t][q4*16+mt*4+r] = bf16(exp(unary[b][t][mt*16+q4*4+r]))
// outStride = bytes per (b,t) row (128 packed, 256 in-place). May alias `in`:
// each row's 32 pairs are handled by one wave (64 thr = 2 rows), loads of a
// row complete before its stores issue (lockstep program order).
__global__ void exp_swizzle_kernel(const float* in, char* outbase, int outStride) {
  const int total = kB * kT * 32;  // pairs
  int p = blockIdx.x * blockDim.x + threadIdx.x;
  const int stride = gridDim.x * blockDim.x;
  for (; p < total; p += stride) {
    const int r = p >> 5;
    const int j0 = (p & 31) << 1;
    const float2 v = *(const float2*)(in + (size_t)r * kN + j0);
    const float e0 = __expf(v.x), e1 = __expf(v.y);
    unsigned u0 = __float_as_uint(e0);
    u0 += 0x7FFFu + ((u0 >> 16) & 1u);  // RNE to bf16
    unsigned u1 = __float_as_uint(e1);
    u1 += 0x7FFFu + ((u1 >> 16) & 1u);
    const unsigned d = (u1 & 0xFFFF0000u) | (u0 >> 16);
    const int pi = ((j0 >> 2) & 3) * 16 + ((j0 >> 4) << 2) + (j0 & 3);
    *(unsigned*)(outbase + (size_t)r * outStride + pi * 2) = d;
  }
}

// ---------- helpers ----------
__device__ __forceinline__ unsigned pack2bf(float lo, float hi) {
  return __builtin_amdgcn_perm(__float_as_uint(hi), __float_as_uint(lo), 0x07060302u);
}

__device__ __forceinline__ bf16x8 pack_bfrag(f32x4 lo, f32x4 hi) {
  union { unsigned u[4]; bf16x8 s; } r;
  r.u[0] = pack2bf(lo.x, lo.y);
  r.u[1] = pack2bf(lo.z, lo.w);
  r.u[2] = pack2bf(hi.x, hi.y);
  r.u[3] = pack2bf(hi.z, hi.w);
  return r.s;
}

__device__ __forceinline__ f32x4 expand2(unsigned u, unsigned v) {
  f32x4 e;
  e.x = __uint_as_float(u << 16);
  e.y = __uint_as_float(u & 0xFFFF0000u);
  e.z = __uint_as_float(v << 16);
  e.w = __uint_as_float(v & 0xFFFF0000u);
  return e;
}

// One step: Q = E*Acc (8 MFMA), Acc' = Q .* eu_rows
__device__ __forceinline__ void crf_step(f32x4 (&ps)[4], const bf16x8 (&af)[4][2],
                                         uint4 u0, uint4 u1) {
  const f32x4 e0 = expand2(u0.x, u0.y);
  const f32x4 e1 = expand2(u0.z, u0.w);
  const f32x4 e2 = expand2(u1.x, u1.y);
  const f32x4 e3 = expand2(u1.z, u1.w);

  const bf16x8 b0 = pack_bfrag(ps[0], ps[1]);
  const bf16x8 b1 = pack_bfrag(ps[2], ps[3]);
  const f32x4 z4 = {0.f, 0.f, 0.f, 0.f};

  f32x4 q0 = __builtin_amdgcn_mfma_f32_16x16x32_bf16(af[0][0], b0, z4, 0, 0, 0);
  f32x4 q1 = __builtin_amdgcn_mfma_f32_16x16x32_bf16(af[1][0], b0, z4, 0, 0, 0);
  f32x4 q2 = __builtin_amdgcn_mfma_f32_16x16x32_bf16(af[2][0], b0, z4, 0, 0, 0);
  f32x4 q3 = __builtin_amdgcn_mfma_f32_16x16x32_bf16(af[3][0], b0, z4, 0, 0, 0);
  q0 = __builtin_amdgcn_mfma_f32_16x16x32_bf16(af[0][1], b1, q0, 0, 0, 0);
  q1 = __builtin_amdgcn_mfma_f32_16x16x32_bf16(af[1][1], b1, q1, 0, 0, 0);
  q2 = __builtin_amdgcn_mfma_f32_16x16x32_bf16(af[2][1], b1, q2, 0, 0, 0);
  q3 = __builtin_amdgcn_mfma_f32_16x16x32_bf16(af[3][1], b1, q3, 0, 0, 0);

  ps[0] = q0 * e0;
  ps[1] = q1 * e1;
  ps[2] = q2 * e2;
  ps[3] = q3 * e3;
}

// Per-wave renorm by exact power of 2 from lane 0's ps[0].x exponent.
// Tile spread bounded (~2^21); 4-step growth <= 2^60 -> no overflow.
__device__ __forceinline__ void renorm(f32x4 (&ps)[4], float& tot_e) {
  const unsigned eref = __builtin_amdgcn_readfirstlane(__float_as_uint(ps[0].x));
  const int e = (int)((eref >> 23) & 0xFFu) - 127;
  const float sc = __uint_as_float((unsigned)(127 - e) << 23);
#pragma unroll
  for (int mt = 0; mt < 4; ++mt) ps[mt] *= sc;
  tot_e += (float)e;
}

__device__ __forceinline__ float exp2i(int d) {  // 2^d for d in [-126, 127]
  return (d <= -127) ? 0.f : __uint_as_float((unsigned)(127 + d) << 23);
}

// ---------- chunk kernel: 4 waves compute one chunk's 64x64 matrix ----------
__global__ __launch_bounds__(256, 2) void chunk_kernel(
    const char* __restrict__ eu, int euStride, const float* __restrict__ trans,
    const int* __restrict__ lengths, char* __restrict__ scr, int scrStride) {
  const int b = blockIdx.x >> 3;
  const int c = blockIdx.x & 7;
  const int w = threadIdx.x >> 6;
  const int lane = threadIdx.x & 63;
  const int col = lane & 15;
  const int q4 = lane >> 4;

  const int len = lengths[b];
  const int start = c * kL;
  if (start >= len) return;  // uniform per block; combine skips these chunks
  const int steps = (len - start < kL) ? (len - start) : kL;

  // Static A-fragments, psi-permuted K (verified rounds 2-3).
  bf16x8 af[4][2];
#pragma unroll
  for (int mt = 0; mt < 4; ++mt) {
#pragma unroll
    for (int kc = 0; kc < 2; ++kc) {
      union { unsigned u[4]; bf16x8 s; } fr;
#pragma unroll
      for (int jp = 0; jp < 4; ++jp) {
        const int j0 = 2 * jp, j1 = 2 * jp + 1;
        const int k0 = (2 * kc + (j0 >> 2)) * 16 + q4 * 4 + (j0 & 3);
        const int k1 = (2 * kc + (j1 >> 2)) * 16 + q4 * 4 + (j1 & 3);
        unsigned e0 = __float_as_uint(__expf(trans[(mt * 16 + col) * kN + k0])) + 0x8000u;
        unsigned e1 = __float_as_uint(__expf(trans[(mt * 16 + col) * kN + k1])) + 0x8000u;
        fr.u[jp] = __builtin_amdgcn_perm(e1, e0, 0x07060302u);
      }
      af[mt][kc] = fr.s;
    }
  }

  // Acc = identity columns: this wave owns columns w*16..w*16+15.
  const int mycol = w * 16 + col;
  f32x4 ps[4];
#pragma unroll
  for (int mt = 0; mt < 4; ++mt) {
    const int rb = mt * 16 + q4 * 4;
    f32x4 v;
    v.x = (rb + 0 == mycol) ? 1.f : 0.f;
    v.y = (rb + 1 == mycol) ? 1.f : 0.f;
    v.z = (rb + 2 == mycol) ? 1.f : 0.f;
    v.w = (rb + 3 == mycol) ? 1.f : 0.f;
    ps[mt] = v;
  }

  // eu ring, depth 4 steps, copy-then-refill (prefetch distance ~4-8 steps;
  // TLP at ~3 waves/SIMD covers the rest).
  const char* ebase = eu + ((size_t)b * kT + start) * (size_t)euStride + q4 * 32;
  uint4 pre[4][2];
#pragma unroll
  for (int i = 0; i < 4; ++i) {
    pre[i][0] = *(const uint4*)(ebase + (size_t)i * euStride);
    pre[i][1] = *(const uint4*)(ebase + (size_t)i * euStride + 16);
  }
  int pfRel = 4;
  const int pfRelMax = kL - 4;  // rows start..start+kL-1 always valid memory
  float tot_e = 0.0f;

  const int G = steps >> 2;
  for (int grp = 0; grp < G; ++grp) {
    const uint4 c0a = pre[0][0], c0b = pre[0][1];
    const uint4 c1a = pre[1][0], c1b = pre[1][1];
    const uint4 c2a = pre[2][0], c2b = pre[2][1];
    const uint4 c3a = pre[3][0], c3b = pre[3][1];
    const char* pf = ebase + (size_t)pfRel * euStride;
#pragma unroll
    for (int i = 0; i < 4; ++i) {
      pre[i][0] = *(const uint4*)(pf + (size_t)i * euStride);
      pre[i][1] = *(const uint4*)(pf + (size_t)i * euStride + 16);
    }
    pfRel += 4;
    if (pfRel > pfRelMax) pfRel = pfRelMax;

    crf_step(ps, af, c0a, c0b);
    crf_step(ps, af, c1a, c1b);
    crf_step(ps, af, c2a, c2b);
    crf_step(ps, af, c3a, c3b);
    renorm(ps, tot_e);
  }
  const int pr = steps & 3;
  if (pr > 0) crf_step(ps, af, pre[0][0], pre[0][1]);
  if (pr > 1) crf_step(ps, af, pre[1][0], pre[1][1]);
  if (pr > 2) crf_step(ps, af, pre[2][0], pre[2][1]);

  // Store 64x16 tile, column-major flat index F = tile*1024 + col*64 + row,
  // mapped to scratch slots of 32 floats with byte stride scrStride.
  const long tileIdx = ((long)b * kC + c) * 4 + w;
#pragma unroll
  for (int mt = 0; mt < 4; ++mt) {
    const long slot = tileIdx * 32 + col * 2 + (mt >> 1);
    char* addr = scr + slot * (long)scrStride + ((mt & 1) * 16 + q4 * 4) * 4;
    *(f32x4*)addr = ps[mt];
  }
  if (lane == 0) {
    const long F = kTileFloats + tileIdx;
    *(float*)(scr + (F >> 5) * (long)scrStride + (F & 31) * 4) = tot_e;
  }
}

// ---------- combine: per batch, chain the chunk matrices (one wave) ----------
__global__ __launch_bounds__(64) void combine_kernel(
    const char* __restrict__ scr, int scrStride, const float* __restrict__ trans,
    const int* __restrict__ lengths, float* __restrict__ out) {
  const int b = blockIdx.x;
  const int j = threadIdx.x;
  const int len = lengths[b];

#define LDS_SCR(F) (*(const float*)(scr + ((long)(F) >> 5) * (long)scrStride + ((F) & 31) * 4))

  // alpha after chunk 0 = column kStart of chunk-0 matrix (wave 0's tile).
  const long t0 = (long)b * kC * 4;
  float a = LDS_SCR(t0 * 1024 + kStart * 64 + j);
  float totE = LDS_SCR(kTileFloats + t0);

  for (int c = 1; c < kC; ++c) {
    if (c * kL >= len) break;  // chunks are contiguous-active
    const long tb = ((long)b * kC + c) * 4;
    float s0 = 0.f, s1 = 0.f, s2 = 0.f, s3 = 0.f;
#pragma unroll
    for (int k16 = 0; k16 < 16; ++k16) {
      const float a0 = __int_as_float(__builtin_amdgcn_readlane(__float_as_int(a), k16));
      const float a1 = __int_as_float(__builtin_amdgcn_readlane(__float_as_int(a), 16 + k16));
      const float a2 = __int_as_float(__builtin_amdgcn_readlane(__float_as_int(a), 32 + k16));
      const float a3 = __int_as_float(__builtin_amdgcn_readlane(__float_as_int(a), 48 + k16));
      s0 = fmaf(LDS_SCR((tb + 0) * 1024 + k16 * 64 + j), a0, s0);
      s1 = fmaf(LDS_SCR((tb + 1) * 1024 + k16 * 64 + j), a1, s1);
      s2 = fmaf(LDS_SCR((tb + 2) * 1024 + k16 * 64 + j), a2, s2);
      s3 = fmaf(LDS_SCR((tb + 3) * 1024 + k16 * 64 + j), a3, s3);
    }
    const float e0 = LDS_SCR(kTileFloats + tb + 0);
    const float e1 = LDS_SCR(kTileFloats + tb + 1);
    const float e2 = LDS_SCR(kTileFloats + tb + 2);
    const float e3 = LDS_SCR(kTileFloats + tb + 3);
    const float em = fmaxf(fmaxf(e0, e1), fmaxf(e2, e3));
    a = s0 * exp2i((int)(e0 - em)) + s1 * exp2i((int)(e1 - em)) +
        s2 * exp2i((int)(e2 - em)) + s3 * exp2i((int)(e3 - em));
    totE += em;

    // renorm alpha (cheap here; exact power of 2 from the wave max)
    float m = a;
#pragma unroll
    for (int mask = 1; mask < 64; mask <<= 1) m = fmaxf(m, __shfl_xor(m, mask));
    const int e = (int)((__float_as_uint(m) >> 23) & 0xFFu) - 127;
    a *= exp2i(-e);
    totE += (float)e;
  }

  float term = a * __expf(trans[kEnd * kN + j]);
#pragma unroll
  for (int mask = 1; mask < 64; mask <<= 1) term += __shfl_xor(term, mask);

  if (j == 0) out[b] = totE * 0.69314718055994530942f + logf(term);
#undef LDS_SCR
}

extern "C" void kernel_launch(void* const* d_in, const int* in_sizes, int n_in,
                              void* d_out, int out_size, void* d_ws, size_t ws_size,
                              hipStream_t stream) {
  const float* unary = (const float*)d_in[0];  // [B, T, N] fp32, 128 MiB
  const float* trans = (const float*)d_in[1];  // [N, N] fp32
  const int* lengths = (const int*)d_in[2];    // [B] int32
  float* out = (float*)d_out;                  // [B] fp32

  const size_t euBytes = (size_t)kB * kT * kN * 2;              // 64 MiB
  const size_t scrBytes = (size_t)(kTileFloats + kNumTiles) * 4;  // ~33.6 MB

  char* euB;
  int euS;
  char* scrB;
  int scrS;
  if (ws_size >= euBytes + scrBytes) {
    euB = (char*)d_ws;
    euS = 128;
    scrB = (char*)d_ws + euBytes;
    scrS = 128;
  } else if (ws_size >= scrBytes) {
    // eu in-place in d_in[0] (lower 128 B of each 256-B row); tiles in ws.
    euB = (char*)d_in[0];
    euS = 256;
    scrB = (char*)d_ws;
    scrS = 128;
  } else {
    // Everything in-place: eu in lower halves, tiles/exps in upper halves
    // (disjoint byte ranges; harness restores inputs before every launch).
    euB = (char*)d_in[0];
    euS = 256;
    scrB = (char*)d_in[0] + 128;
    scrS = 256;
  }

  exp_swizzle_kernel<<<dim3(4096), dim3(256), 0, stream>>>(unary, euB, euS);
  chunk_kernel<<<dim3(kB * kC), dim3(256), 0, stream>>>(euB, euS, trans, lengths,
                                                        scrB, scrS);
  combine_kernel<<<dim3(kB), dim3(64), 0, stream>>>(scrB, scrS, trans, lengths, out);
}